// Round 2
// 1280.522 us; speedup vs baseline: 1.1570x; 1.1570x over previous
//
#include <hip/hip_runtime.h>

typedef short s16x8 __attribute__((ext_vector_type(8)));
typedef unsigned short u16x8 __attribute__((ext_vector_type(8)));
typedef unsigned short u16x4 __attribute__((ext_vector_type(4)));
typedef float f32x4 __attribute__((ext_vector_type(4)));

#define CB 2
#define CS 4096
#define CD 2048
#define CH 16
#define CSEG 512
#define CDH 8192

__device__ __forceinline__ unsigned short f2b(float f) {
  union { float f; unsigned u; } v; v.f = f;
  unsigned r = v.u + 0x7fffu + ((v.u >> 16) & 1u);
  return (unsigned short)(r >> 16);
}
__device__ __forceinline__ float b2f(unsigned short b) {
  union { unsigned u; float f; } v; v.u = ((unsigned)b) << 16;
  return v.f;
}
__device__ __forceinline__ f32x4 mfma16(s16x8 a, s16x8 b, f32x4 c) {
  return __builtin_amdgcn_mfma_f32_16x16x32_bf16(a, b, c, 0, 0, 0);
}
__device__ __forceinline__ void async16(const unsigned short* g, unsigned short* l) {
  __builtin_amdgcn_global_load_lds((const __attribute__((address_space(1))) void*)g,
                                   (__attribute__((address_space(3))) void*)l, 16, 0, 0);
}

// ---------------- fp32 -> bf16 convert ----------------
__global__ void convert_bf16_k(const float* __restrict__ in, unsigned short* __restrict__ out) {
  size_t i = ((size_t)blockIdx.x * 256 + threadIdx.x) * 4;
  f32x4 v = *(const f32x4*)(in + i);
  u16x4 o;
  #pragma unroll
  for (int e = 0; e < 4; e++) o[e] = f2b(v[e]);
  *(u16x4*)(out + i) = o;
}

// ---------------- fp32 RxC -> bf16 CxR transpose ----------------
__global__ void transpose_bf16_k(const float* __restrict__ in, unsigned short* __restrict__ out,
                                 int R, int C) {
  __shared__ float tile[32][33];
  int c0 = blockIdx.x * 32, r0 = blockIdx.y * 32;
  int tx = threadIdx.x & 31, ty = threadIdx.x >> 5;
  #pragma unroll
  for (int i = 0; i < 32; i += 8)
    tile[ty + i][tx] = in[(size_t)(r0 + ty + i) * C + c0 + tx];
  __syncthreads();
  #pragma unroll
  for (int i = 0; i < 32; i += 8)
    out[(size_t)(c0 + ty + i) * R + r0 + tx] = f2b(tile[tx][ty + i]);
}

// ---- bf16 [B*S, 2048] -> per-(b,h) transposed [ (b*16+h)*128+v ][4096 s ]; K gets elu+1 ----
__global__ void transpose_kv_k(const unsigned short* __restrict__ kb,
                               const unsigned short* __restrict__ vb,
                               unsigned short* __restrict__ KT,
                               unsigned short* __restrict__ VT) {
  __shared__ unsigned short kt_[64][72];  // 144 B rows (16B-aligned)
  __shared__ unsigned short vt_[64][72];
  const int t = threadIdx.x;
  const int r0 = blockIdx.x * 64, c0 = blockIdx.y * 64;
  {
    int row = t >> 2, cc = (t & 3) * 16;
    size_t g = (size_t)(r0 + row) * CD + c0 + cc;
    #pragma unroll
    for (int u = 0; u < 2; u++) {
      u16x8 kv = *(const u16x8*)(kb + g + u * 8);
      u16x8 vv = *(const u16x8*)(vb + g + u * 8);
      u16x8 ko;
      #pragma unroll
      for (int e = 0; e < 8; e++) {
        float f = b2f(kv[e]);
        ko[e] = f2b(f > 0.f ? f + 1.f : __expf(f));
      }
      *(u16x8*)&kt_[row][cc + u * 8] = ko;
      *(u16x8*)&vt_[row][cc + u * 8] = vv;
    }
  }
  __syncthreads();
  {
    int vc = t >> 2, s0 = (t & 3) * 16;
    int c = c0 + vc;
    int h = c >> 7, v = c & 127;
    int b = r0 >> 12, sbase = (r0 & 4095) + s0;
    size_t obase = ((size_t)((b * 16 + h) * 128 + v) << 12) + sbase;
    u16x8 wk0, wk1, wv0, wv1;
    #pragma unroll
    for (int e = 0; e < 8; e++) {
      wk0[e] = kt_[s0 + e][vc];      wv0[e] = vt_[s0 + e][vc];
      wk1[e] = kt_[s0 + 8 + e][vc];  wv1[e] = vt_[s0 + 8 + e][vc];
    }
    *(u16x8*)&KT[obase] = wk0;  *(u16x8*)&KT[obase + 8] = wk1;
    *(u16x8*)&VT[obase] = wv0;  *(u16x8*)&VT[obase + 8] = wv1;
  }
}

// ======================================================================
// GEMM 256x256 tile, BK=64, 8 waves, 4-phase pipelined schedule with
// counted vmcnt, XOR-swizzled LDS (pre-swizzled global source), setprio.
// C[M,N] = A[M,K] @ BT[N,K]^T (bf16 in, MFMA, bf16 out)
// EPI: 1 = bf16 out, 2 = bias+relu, 4 = bias
// Requires: M%256==0, N%256==0, K%64==0, K>=128, grid=(M/256)*(N/256)%8==0
// ======================================================================
template <int EPI>
__global__ __launch_bounds__(512, 2) void gemm256(const unsigned short* __restrict__ A,
                                                  const unsigned short* __restrict__ BT,
                                                  const float* __restrict__ bias,
                                                  unsigned short* __restrict__ C,
                                                  int M, int N, int K) {
  // 2 x [256 rows][64 cols] bf16 per matrix = 128 KiB total
  __shared__ unsigned short As[2 * 16384];
  __shared__ unsigned short Bs[2 * 16384];

  const int t = threadIdx.x, wave = t >> 6, lane = t & 63;
  const int fr = lane & 15, quad = lane >> 4;
  const int wm = wave >> 2, wn = wave & 3;   // 2 x 4 wave grid
  const int wave8 = wave * 8;

  // ---- block swizzle: bijective XCD chunking (nwg%8==0) + 8-m-tile stripes ----
  const int nwg = (int)gridDim.x;
  const int q8 = nwg >> 3;
  const int wg = (blockIdx.x & 7) * q8 + (blockIdx.x >> 3);
  const int nN = N >> 8;
  const int stripe = wg / (8 * nN), rem = wg % (8 * nN);
  const int m0 = (stripe * 8 + (rem & 7)) << 8;
  const int n0 = (rem >> 3) << 8;

  const int NT = K >> 6;

  // staging: thread covers row (t>>3), 16B slot (t&7); global col pre-swizzled
  // so that linear global_load_lds dest yields XOR-swizzled LDS contents.
  const int scol = ((t & 7) ^ ((t >> 3) & 7)) * 8;  // elements
  const unsigned short* Asrc = A + (size_t)(m0 + (t >> 3)) * K + scol;
  const unsigned short* Bsrc = BT + (size_t)(n0 + (t >> 3)) * K + scol;

  // fragment-read swizzled 16B-slot offsets (elements): logical byte
  // (k*64+quad*16) at row r -> physical ((k*4+quad)^(r&7))*16, r&7 == fr&7
  const int sw0 = ((quad ^ (fr & 7)) * 8);
  const int sw1 = (((4 + quad) ^ (fr & 7)) * 8);
  const int arow = wm * 128 + fr;  // + MH*64 + m*16
  const int brow = wn * 64 + fr;   // + NH*32 + n*16

  f32x4 c00[4][2] = {}, c01[4][2] = {}, c11[4][2] = {}, c10[4][2] = {};
  s16x8 aC[4][2], b0f[2][2], b1f[2][2];

#define STG2(SRC, LB, HR, KT)                                                            \
  do {                                                                                   \
    async16((SRC) + (size_t)(HR) * K + (size_t)(KT) * 64, (LB) + ((HR) + wave8) * 64);   \
    async16((SRC) + (size_t)((HR) + 64) * K + (size_t)(KT) * 64,                         \
            (LB) + ((HR) + 64 + wave8) * 64);                                            \
  } while (0)

#define LDA4(DST, BASE, ROFF)                                          \
  _Pragma("unroll") for (int m_ = 0; m_ < 4; m_++) {                   \
    const unsigned short* p_ = (BASE) + (size_t)(arow + (ROFF) + m_ * 16) * 64; \
    DST[m_][0] = *(const s16x8*)(p_ + sw0);                            \
    DST[m_][1] = *(const s16x8*)(p_ + sw1);                            \
  }

#define LDB2(DST, BASE, ROFF)                                          \
  _Pragma("unroll") for (int n_ = 0; n_ < 2; n_++) {                   \
    const unsigned short* p_ = (BASE) + (size_t)(brow + (ROFF) + n_ * 16) * 64; \
    DST[n_][0] = *(const s16x8*)(p_ + sw0);                            \
    DST[n_][1] = *(const s16x8*)(p_ + sw1);                            \
  }

#define MFMA_Q(CC, AV, BV)                                             \
  _Pragma("unroll") for (int k_ = 0; k_ < 2; k_++)                     \
  _Pragma("unroll") for (int m_ = 0; m_ < 4; m_++)                     \
  _Pragma("unroll") for (int n_ = 0; n_ < 2; n_++)                     \
      CC[m_][n_] = mfma16(AV[m_][k_], BV[n_][k_], CC[m_][n_]);

  // ---- prologue: stage tile0 (all) + tile1 (all) in steady-state order ----
  {
    unsigned short* A0 = As;           unsigned short* B0 = Bs;
    unsigned short* A1 = As + 16384;   unsigned short* B1 = Bs + 16384;
    STG2(Bsrc, B0, 0, 0);   STG2(Bsrc, B0, 128, 0);
    STG2(Asrc, A0, 0, 0);   STG2(Asrc, A0, 128, 0);
    STG2(Bsrc, B1, 0, 1);   STG2(Bsrc, B1, 128, 1);
    STG2(Asrc, A1, 0, 1);   STG2(Asrc, A1, 128, 1);
  }
  asm volatile("s_waitcnt vmcnt(8)" ::: "memory");   // tile0 resident
  __builtin_amdgcn_s_barrier();

  for (int tt = 0; tt < NT; tt++) {
    const int cur = tt & 1;
    unsigned short* Ac = As + (cur << 14);
    unsigned short* Bc = Bs + (cur << 14);
    const int k2 = (tt + 2 < NT) ? tt + 2 : NT - 1;  // clamp: stages land in dead regions

    // ---- phase 1: Q(0,0)  (12 ds_reads, no stage) ----
    LDA4(aC, Ac, 0)
    LDB2(b0f, Bc, 0)
    __builtin_amdgcn_s_barrier();
    asm volatile("s_waitcnt lgkmcnt(0)" ::: "memory");
    __builtin_amdgcn_sched_barrier(0);
    __builtin_amdgcn_s_setprio(1);
    MFMA_Q(c00, aC, b0f)
    __builtin_amdgcn_s_setprio(0);
    __builtin_amdgcn_s_barrier();

    // ---- phase 2: Q(0,1)  (4 ds_reads; B(t) dies here) ----
    LDB2(b1f, Bc, 32)
    __builtin_amdgcn_s_barrier();
    asm volatile("s_waitcnt lgkmcnt(0)" ::: "memory");
    __builtin_amdgcn_sched_barrier(0);
    __builtin_amdgcn_s_setprio(1);
    MFMA_Q(c01, aC, b1f)
    __builtin_amdgcn_s_setprio(0);
    __builtin_amdgcn_s_barrier();

    // ---- phase 3: Q(1,1)  (8 ds_reads; stage B(t+2) into dead B region) ----
    LDA4(aC, Ac, 64)
    STG2(Bsrc, Bc, 0, k2);
    STG2(Bsrc, Bc, 128, k2);
    __builtin_amdgcn_s_barrier();
    asm volatile("s_waitcnt lgkmcnt(0)" ::: "memory");
    __builtin_amdgcn_sched_barrier(0);
    __builtin_amdgcn_s_setprio(1);
    MFMA_Q(c11, aC, b1f)
    __builtin_amdgcn_s_setprio(0);
    __builtin_amdgcn_s_barrier();

    // ---- phase 4: Q(1,0)  (0 ds_reads; counted vmcnt guarantees tile t+1;
    //                        stage A(t+2) into dead A region) ----
    asm volatile("s_waitcnt vmcnt(4)" ::: "memory");
    STG2(Asrc, Ac, 0, k2);
    STG2(Asrc, Ac, 128, k2);
    __builtin_amdgcn_s_barrier();
    __builtin_amdgcn_s_setprio(1);
    MFMA_Q(c10, aC, b0f)
    __builtin_amdgcn_s_setprio(0);
    __builtin_amdgcn_s_barrier();
  }

  // ---- epilogue ----
  const int er = quad * 4;
#define EPIQ(CC, MH, NH)                                               \
  _Pragma("unroll") for (int m_ = 0; m_ < 4; m_++) {                   \
    int row_ = m0 + wm * 128 + (MH)*64 + m_ * 16 + er;                 \
    _Pragma("unroll") for (int n_ = 0; n_ < 2; n_++) {                 \
      int col_ = n0 + wn * 64 + (NH)*32 + n_ * 16 + fr;                \
      float bv_ = (EPI >= 2) ? bias[col_] : 0.f;                       \
      _Pragma("unroll") for (int r_ = 0; r_ < 4; r_++) {               \
        float v_ = CC[m_][n_][r_];                                     \
        size_t idx_ = (size_t)(row_ + r_) * N + col_;                  \
        if (EPI == 1) C[idx_] = f2b(v_);                               \
        else if (EPI == 2) { v_ += bv_; C[idx_] = f2b(v_ > 0.f ? v_ : 0.f); } \
        else { v_ += bv_; C[idx_] = f2b(v_); }                         \
      }                                                                \
    }                                                                  \
  }
  EPIQ(c00, 0, 0)
  EPIQ(c01, 0, 1)
  EPIQ(c11, 1, 1)
  EPIQ(c10, 1, 0)
#undef EPIQ
#undef MFMA_Q
#undef LDB2
#undef LDA4
#undef STG2
}

// ------- per-segment KV sums via MFMA: mseg[v][d] = sum_s V[s][v]*sigK[s][d] -------
__global__ void kvsum_k(const unsigned short* __restrict__ KT, const unsigned short* __restrict__ VT,
                        float* __restrict__ memsegT, float* __restrict__ zseg) {
  __shared__ unsigned short As[128 * 32];
  __shared__ unsigned short Bs[128 * 32];
  const int seg = blockIdx.x, b = blockIdx.y, h = blockIdx.z;
  const int bh = b * 16 + h;
  const int t = threadIdx.x, wave = t >> 6, lane = t & 63;
  const int fr = lane & 15, fq = (lane >> 4) * 8;
  const int wr = (wave >> 1) * 64, wc = (wave & 1) * 64;

  f32x4 acc[4][4] = {};
  const size_t sbase = (size_t)seg * 512;
  const unsigned short* Ag = VT + ((size_t)(bh * 128 + wave * 32 + (lane >> 2)) << 12) + sbase + (lane & 3) * 8;
  const unsigned short* Bg = KT + ((size_t)(bh * 128 + wave * 32 + (lane >> 2)) << 12) + sbase + (lane & 3) * 8;
  unsigned short* Al = As + (wave * 32) * 32;
  unsigned short* Bl = Bs + (wave * 32) * 32;
  const size_t r16 = (size_t)16 << 12;

  for (int kk = 0; kk < 512; kk += 32) {
    __syncthreads();
    async16(Ag + kk, Al);
    async16(Ag + kk + r16, Al + 16 * 32);
    async16(Bg + kk, Bl);
    async16(Bg + kk + r16, Bl + 16 * 32);
    __syncthreads();
    s16x8 af[4], bfr[4];
    #pragma unroll
    for (int i = 0; i < 4; i++) af[i] = *(const s16x8*)&As[(wr + i * 16 + fr) * 32 + fq];
    #pragma unroll
    for (int j = 0; j < 4; j++) bfr[j] = *(const s16x8*)&Bs[(wc + j * 16 + fr) * 32 + fq];
    #pragma unroll
    for (int i = 0; i < 4; i++)
      #pragma unroll
      for (int j = 0; j < 4; j++)
        acc[i][j] = mfma16(af[i], bfr[j], acc[i][j]);
  }

  const size_t obase = (size_t)((seg * 2 + b) * 16 + h) * 16384;
  const int er = (lane >> 4) * 4, ec = lane & 15;
  #pragma unroll
  for (int i = 0; i < 4; i++)
    #pragma unroll
    for (int j = 0; j < 4; j++)
      #pragma unroll
      for (int r = 0; r < 4; r++)
        memsegT[obase + (size_t)(wr + i * 16 + er + r) * 128 + wc + j * 16 + ec] = acc[i][j][r];

  if (t < 128) {
    const unsigned short* zp = KT + ((size_t)(bh * 128 + t) << 12) + sbase;
    float z = 0.f;
    #pragma unroll 4
    for (int u = 0; u < 64; u++) {
      u16x8 kv = *(const u16x8*)(zp + u * 8);
      #pragma unroll
      for (int e = 0; e < 8; e++) z += b2f(kv[e]);
    }
    zseg[(size_t)((seg * 2 + b) * 16 + h) * 128 + t] = z;
  }
}

// ---------------- exclusive prefix over segments ----------------
__global__ void prefix_k(const float* __restrict__ memsegT, const float* __restrict__ zseg,
                         unsigned short* __restrict__ memPT, float* __restrict__ zP) {
  const int bh = blockIdx.x, t = threadIdx.x;
  for (int e = t; e < 16384; e += 256) {
    float a = 0.f;
    #pragma unroll
    for (int s = 0; s < 8; s++) {
      size_t idx = (size_t)(s * 32 + bh) * 16384 + e;
      memPT[idx] = f2b(a);
      a += memsegT[idx];
    }
  }
  if (t < 128) {
    float a = 1.f / 128.f;
    #pragma unroll
    for (int s = 0; s < 8; s++) {
      size_t idx = (size_t)(s * 32 + bh) * 128 + t;
      zP[idx] = a;
      a += zseg[idx];
    }
  }
}

// ---------------- fused segment attention (flash) + memory retrieval + gate ----------------
#define PD 136
#define PPS 40
__global__ void attn_k(const unsigned short* __restrict__ qb,
                       const unsigned short* __restrict__ kb,
                       const unsigned short* __restrict__ VT,
                       const unsigned short* __restrict__ memPT,
                       const float* __restrict__ zPv,
                       const float* __restrict__ betas,
                       unsigned short* __restrict__ att) {
  const int qt = blockIdx.x, seg = blockIdx.y, bh = blockIdx.z;
  const int b = bh >> 4, h = bh & 15;
  const int t = threadIdx.x, wave = t >> 6, lane = t & 63;
  const int fr = lane & 15, quad = lane >> 4, fq = quad * 8;

  __shared__ unsigned short Qs[64 * PD];
  __shared__ unsigned short SB[64 * PD];    // sig_q, later P
  __shared__ unsigned short KB[32 * PD];    // mem quarters / K tiles
  __shared__ unsigned short VTs[128 * PPS]; // V^T tile [v][s]
  __shared__ float denomS[64];
  __shared__ float dpart[4][64];
  __shared__ float zPs[128];

  unsigned short* SQ = SB;
  unsigned short* Ps = SB;

  const size_t qrow0 = (size_t)b * CS + (size_t)seg * CSEG + (size_t)qt * 64;
  const size_t mbase = (size_t)(seg * 32 + bh) * 16384;
  const size_t vtbase = ((size_t)(bh * 128) << 12) + (size_t)seg * 512;

  // stage Q (pre-scaled) and sig_q
  {
    int row = t >> 2, c0 = (t & 3) * 32;
    const unsigned short* src = qb + (qrow0 + row) * (size_t)CD + (size_t)h * 128 + c0;
    #pragma unroll
    for (int u = 0; u < 4; u++) {
      u16x8 qv = *(const u16x8*)(src + u * 8);
      u16x8 qo, so;
      #pragma unroll
      for (int e = 0; e < 8; e++) {
        float f = b2f(qv[e]);
        qo[e] = f2b(f * 0.08838834764831845f);
        so[e] = f2b(f > 0.f ? f + 1.f : __expf(f));
      }
      *(u16x8*)&Qs[row * PD + c0 + u * 8] = qo;
      *(u16x8*)&SQ[row * PD + c0 + u * 8] = so;
    }
    if (t < 128) zPs[t] = zPv[(size_t)(seg * 32 + bh) * 128 + t];
  }
  __syncthreads();

  // denominators: sig_q . zP (parallel over 4 chunks)
  {
    int row = t & 63, part = t >> 6;
    float s = 0.f;
    #pragma unroll
    for (int i = 0; i < 32; i++) {
      int d = part * 32 + i;
      s += b2f(SQ[row * PD + d]) * zPs[d];
    }
    dpart[part][row] = s;
  }
  __syncthreads();
  if (t < 64) denomS[t] = dpart[0][t] + dpart[1][t] + dpart[2][t] + dpart[3][t];

  // att_mem = sig_q @ memP  (memP staged in 32-row quarters)
  f32x4 om[8] = {};
  for (int qd = 0; qd < 4; qd++) {
    __syncthreads();
    {
      int row = t >> 3, c0 = (t & 7) * 16;
      const unsigned short* msrc = memPT + mbase + (size_t)(qd * 32 + row) * 128 + c0;
      *(u16x8*)&KB[row * PD + c0] = *(const u16x8*)msrc;
      *(u16x8*)&KB[row * PD + c0 + 8] = *(const u16x8*)(msrc + 8);
    }
    __syncthreads();
    #pragma unroll
    for (int jj = 0; jj < 2; jj++)
      #pragma unroll
      for (int kf = 0; kf < 4; kf++) {
        s16x8 a = *(const s16x8*)&SQ[(wave * 16 + fr) * PD + kf * 32 + fq];
        s16x8 bb = *(const s16x8*)&KB[(jj * 16 + fr) * PD + kf * 32 + fq];
        om[qd * 2 + jj] = mfma16(a, bb, om[qd * 2 + jj]);
      }
  }

  // causal attention, online softmax, 32-key tiles
  f32x4 od[8] = {};
  float mrow[4], lrow[4];
  #pragma unroll
  for (int r = 0; r < 4; r++) { mrow[r] = -1e30f; lrow[r] = 0.f; }

  const int nkt = qt * 2 + 2;
  for (int kt = 0; kt < nkt; kt++) {
    __syncthreads();
    {
      // K tile (normal layout) for scores
      int row = t >> 3, c0 = (t & 7) * 16;
      size_t g = ((size_t)b * CS + (size_t)seg * CSEG + (size_t)kt * 32 + row) * CD + (size_t)h * 128 + c0;
      *(u16x8*)&KB[row * PD + c0] = *(const u16x8*)(kb + g);
      *(u16x8*)&KB[row * PD + c0 + 8] = *(const u16x8*)(kb + g + 8);
      // V^T tile [128 v][32 s] from pre-transposed global (vector loads)
      int v = t >> 1, sc = (t & 1) * 16;
      const unsigned short* vsrc = VT + vtbase + ((size_t)v << 12) + kt * 32 + sc;
      *(u16x8*)&VTs[v * PPS + sc] = *(const u16x8*)vsrc;
      *(u16x8*)&VTs[v * PPS + sc + 8] = *(const u16x8*)(vsrc + 8);
    }
    __syncthreads();

    f32x4 sc[2] = {};
    #pragma unroll
    for (int kf = 0; kf < 4; kf++) {
      s16x8 a = *(const s16x8*)&Qs[(wave * 16 + fr) * PD + kf * 32 + fq];
      #pragma unroll
      for (int nt = 0; nt < 2; nt++) {
        s16x8 bb = *(const s16x8*)&KB[(nt * 16 + fr) * PD + kf * 32 + fq];
        sc[nt] = mfma16(a, bb, sc[nt]);
      }
    }

    if (kt >= 2 * qt) {
      #pragma unroll
      for (int nt = 0; nt < 2; nt++)
        #pragma unroll
        for (int r = 0; r < 4; r++) {
          int qi = qt * 64 + wave * 16 + quad * 4 + r;
          int ki = kt * 32 + nt * 16 + fr;
          if (ki > qi) sc[nt][r] = -1e30f;
        }
    }

    float al[4], pv[2][4];
    #pragma unroll
    for (int r = 0; r < 4; r++) {
      float mx = fmaxf(sc[0][r], sc[1][r]);
      #pragma unroll
      for (int xm = 8; xm >= 1; xm >>= 1) mx = fmaxf(mx, __shfl_xor(mx, xm, 64));
      float mn = fmaxf(mrow[r], mx);
      al[r] = __expf(mrow[r] - mn);
      mrow[r] = mn;
      float ps = 0.f;
      #pragma unroll
      for (int nt = 0; nt < 2; nt++) {
        float p = __expf(sc[nt][r] - mn);
        pv[nt][r] = p;
        ps += p;
      }
      #pragma unroll
      for (int xm = 8; xm >= 1; xm >>= 1) ps += __shfl_xor(ps, xm, 64);
      lrow[r] = lrow[r] * al[r] + ps;
    }
    #pragma unroll
    for (int j = 0; j < 8; j++)
      #pragma unroll
      for (int r = 0; r < 4; r++) od[j][r] *= al[r];

    #pragma unroll
    for (int nt = 0; nt < 2; nt++)
      #pragma unroll
      for (int r = 0; r < 4; r++)
        Ps[(wave * 16 + quad * 4 + r) * PPS + nt * 16 + fr] = f2b(pv[nt][r]);

    s16x8 a = *(const s16x8*)&Ps[(wave * 16 + fr) * PPS + fq];
    #pragma unroll
    for (int j = 0; j < 8; j++) {
      s16x8 bb = *(const s16x8*)&VTs[(j * 16 + fr) * PPS + fq];
      od[j] = mfma16(a, bb, od[j]);
    }
  }

  // gate-combine epilogue
  #pragma unroll
  for (int j = 0; j < 8; j++) {
    int vcol = j * 16 + fr;
    float g = 1.f / (1.f + __expf(-betas[h * 128 + vcol]));
    #pragma unroll
    for (int r = 0; r < 4; r++) {
      int rowl = wave * 16 + quad * 4 + r;
      float amem = om[j][r] / denomS[rowl];
      float adot = od[j][r] / lrow[r];
      att[(qrow0 + rowl) * (size_t)CD + (size_t)h * 128 + vcol] = f2b(g * amem + (1.f - g) * adot);
    }
  }
}

// ---------------- residual + LayerNorm (y in bf16) ----------------
__global__ void ln_k(const unsigned short* __restrict__ y, const float* __restrict__ x,
                     const float* __restrict__ gam, const float* __restrict__ bet,
                     float* __restrict__ out) {
  const int row = blockIdx.x, t = threadIdx.x;
  const int lane = t & 63, wave = t >> 6;
  const unsigned short* yr = y + (size_t)row * CD;
  const float* xr = x + (size_t)row * CD;
  float v[8];
  float s = 0.f, ss = 0.f;
  u16x8 a8 = *(const u16x8*)(yr + t * 8);
  #pragma unroll
  for (int u = 0; u < 2; u++) {
    f32x4 c = *(const f32x4*)(xr + t * 8 + u * 4);
    #pragma unroll
    for (int e = 0; e < 4; e++) {
      float r = b2f(a8[u * 4 + e]) + c[e];
      v[u * 4 + e] = r; s += r; ss += r * r;
    }
  }
  #pragma unroll
  for (int off = 32; off >= 1; off >>= 1) {
    s += __shfl_xor(s, off, 64);
    ss += __shfl_xor(ss, off, 64);
  }
  __shared__ float red[8];
  if (lane == 0) { red[wave] = s; red[4 + wave] = ss; }
  __syncthreads();
  s = red[0] + red[1] + red[2] + red[3];
  ss = red[4] + red[5] + red[6] + red[7];
  const float mu = s * (1.f / 2048.f);
  const float var = ss * (1.f / 2048.f) - mu * mu;
  const float rs = rsqrtf(var + 1e-5f);
  #pragma unroll
  for (int u = 0; u < 2; u++)
    #pragma unroll
    for (int e = 0; e < 4; e++) {
      int c = t * 8 + u * 4 + e;
      out[(size_t)row * CD + c] = (v[u * 4 + e] - mu) * rs * gam[c] + bet[c];
    }
}

extern "C" void kernel_launch(void* const* d_in, const int* in_sizes, int n_in,
                              void* d_out, int out_size, void* d_ws, size_t ws_size,
                              hipStream_t stream) {
  const float* xf   = (const float*)d_in[0];
  const float* Wq   = (const float*)d_in[1];
  const float* Wk   = (const float*)d_in[2];
  const float* Wv   = (const float*)d_in[3];
  const float* Wo   = (const float*)d_in[4];
  const float* bet  = (const float*)d_in[5];
  const float* W1   = (const float*)d_in[6];
  const float* b1   = (const float*)d_in[7];
  const float* W2   = (const float*)d_in[8];
  const float* b2   = (const float*)d_in[9];
  const float* lng  = (const float*)d_in[10];
  const float* lnb  = (const float*)d_in[11];
  float* out = (float*)d_out;

  // ---- 224 MB workspace, lifetime-overlaid ----
  const size_t MB = 1024ull * 1024ull;
  char* w = (char*)d_ws;
  unsigned short* qbuf  = (unsigned short*)(w + 0 * MB);    // dead after attn
  unsigned short* kbuf  = (unsigned short*)(w + 32 * MB);   // dead after attn
  unsigned short* vbuf  = (unsigned short*)(w + 64 * MB);   // dead after transpose_kv
  unsigned short* xb    = (unsigned short*)(w + 96 * MB);   // dead after QKV gemms
  unsigned short* VTg   = (unsigned short*)(w + 96 * MB);   // overlays xb; dead after attn
  unsigned short* KTg   = (unsigned short*)(w + 128 * MB);  // dead after kvsum
  unsigned short* attb  = (unsigned short*)(w + 128 * MB);  // overlays KTg
  float*          msegT = (float*)(w + 64 * MB);            // overlays vbuf (16MB)
  unsigned short* memPT = (unsigned short*)(w + 80 * MB);   // 8MB
  float*          zsegb = (float*)(w + 88 * MB);
  float*          zPb   = (float*)(w + 89 * MB);
  unsigned short* aob   = (unsigned short*)(w + 0 * MB);    // overlays qbuf (post-attn)
  unsigned short* hb    = (unsigned short*)(w + 32 * MB);   // 128MB: overlays kbuf..attb (post-Wo)
  unsigned short* ybb   = (unsigned short*)(w + 0 * MB);    // overlays aob (post-W1)
  unsigned short* W1T   = (unsigned short*)(w + 160 * MB);  // dead after W1 gemm
  unsigned short* W2T   = (unsigned short*)(w + 160 * MB);  // overlays W1T (post-W1)
  unsigned short* WqT   = (unsigned short*)(w + 192 * MB);
  unsigned short* WkT   = (unsigned short*)(w + 200 * MB);
  unsigned short* WvT   = (unsigned short*)(w + 208 * MB);
  unsigned short* WoT   = (unsigned short*)(w + 216 * MB);

  convert_bf16_k<<<dim3(16384), 256, 0, stream>>>(xf, xb);
  transpose_bf16_k<<<dim3(64, 64), 256, 0, stream>>>(Wq, WqT, 2048, 2048);
  transpose_bf16_k<<<dim3(64, 64), 256, 0, stream>>>(Wk, WkT, 2048, 2048);
  transpose_bf16_k<<<dim3(64, 64), 256, 0, stream>>>(Wv, WvT, 2048, 2048);
  transpose_bf16_k<<<dim3(64, 64), 256, 0, stream>>>(Wo, WoT, 2048, 2048);
  transpose_bf16_k<<<dim3(256, 64), 256, 0, stream>>>(W1, W1T, 2048, 8192);

  gemm256<1><<<dim3(256), 512, 0, stream>>>(xb, WqT, nullptr, qbuf, 8192, 2048, 2048);
  gemm256<1><<<dim3(256), 512, 0, stream>>>(xb, WkT, nullptr, kbuf, 8192, 2048, 2048);
  gemm256<1><<<dim3(256), 512, 0, stream>>>(xb, WvT, nullptr, vbuf, 8192, 2048, 2048);

  transpose_kv_k<<<dim3(128, 32), 256, 0, stream>>>(kbuf, vbuf, KTg, VTg);
  kvsum_k<<<dim3(8, 2, 16), 256, 0, stream>>>(KTg, VTg, msegT, zsegb);
  prefix_k<<<dim3(32), 256, 0, stream>>>(msegT, zsegb, memPT, zPb);
  attn_k<<<dim3(8, 8, 32), 256, 0, stream>>>(qbuf, kbuf, VTg, memPT, zPb, bet, attb);

  gemm256<1><<<dim3(256), 512, 0, stream>>>(attb, WoT, nullptr, aob, 8192, 2048, 2048);
  gemm256<2><<<dim3(1024), 512, 0, stream>>>(aob, W1T, b1, hb, 8192, 8192, 2048);
  transpose_bf16_k<<<dim3(64, 256), 256, 0, stream>>>(W2, W2T, 8192, 2048);
  gemm256<4><<<dim3(256), 512, 0, stream>>>(hb, W2T, b2, ybb, 8192, 2048, 8192);
  ln_k<<<dim3(8192), 256, 0, stream>>>(ybb, xf, lng, lnb, out);
}